// Round 7
// baseline (402.294 us; speedup 1.0000x reference)
//
#include <hip/hip_runtime.h>

typedef short  s16x8  __attribute__((ext_vector_type(8)));
typedef float  f32x16 __attribute__((ext_vector_type(16)));
typedef unsigned short u16;
typedef unsigned int   u32;

#define MFMA32(a,b,c) __builtin_amdgcn_mfma_f32_32x32x16_bf16((a),(b),(c),0,0,0)
#define KCLS 100
#define VMCNT(n) asm volatile("s_waitcnt vmcnt(" #n ")" ::: "memory")
#define BAR()    __builtin_amdgcn_s_barrier()

__device__ __forceinline__ u16 f2bf(float f) {
  return (u16)(__builtin_bit_cast(unsigned, f) >> 16);   // trunc; error budget huge
}

__device__ __forceinline__ u32 pk2bf(float lo, float hi) {   // trunc-pack 2 f32 -> 2 bf16
#if __has_builtin(__builtin_amdgcn_perm)
  return __builtin_amdgcn_perm(__builtin_bit_cast(u32, hi),
                               __builtin_bit_cast(u32, lo), 0x07060302u);
#else
  return (__builtin_bit_cast(u32, lo) >> 16) | (__builtin_bit_cast(u32, hi) & 0xffff0000u);
#endif
}

__device__ __forceinline__ float tanh_fast(float x) {
  float e = __builtin_amdgcn_exp2f(x * 2.8853900817779268f);
  return 1.0f - 2.0f * __builtin_amdgcn_rcpf(e + 1.0f);
}

__device__ __forceinline__ void ld_lds16(const void* g, void* l) {
  __builtin_amdgcn_global_load_lds(
      (const __attribute__((address_space(1))) unsigned char*)g,
      (__attribute__((address_space(3))) unsigned char*)l, 16, 0, 0);
}

// ============ prep: emit fragment-ordered bf16 tensors + zero accumulators ============
// r5-proven: every branch is coalesced fp32 tile load -> LDS transpose (stride-65,
// conflict-free) -> uint4 frag writes. Zero branch extended to cover cnt[].
// Fragment = 1 KB: [lane64][8 bf16]; lane&31 = row/col-in-tile, lane>>5 = k-half.
// xF  [b][frag = gks*2+ph]   p = ph*32+(lane&31), c = gks*16+(lane>>5)*8+j
// W1F [k][frag = gks*2+mt]   m = mt*32+(lane&31), c = (frag>>1)*16+(lane>>5)*8+j
// W2F [k][frag = kb*4+m4]    m = m4*32+(lane&31), c = kb*16+(lane>>5)*8+j
// W3F [k][frag = kb]         m = lane&31,         c = kb*16+(lane>>5)*8+j
__global__ void prep(const float* __restrict__ x, const float* __restrict__ w1,
                     const float* __restrict__ w2, const float* __restrict__ w3,
                     u16* __restrict__ xF, u16* __restrict__ W1F,
                     u16* __restrict__ W2F, u16* __restrict__ W3F,
                     float* __restrict__ fz, float* __restrict__ out2) {
  __shared__ float tile[64][65];
  const int bid = blockIdx.x, t = threadIdx.x;
  if (bid == 0 && t < 2) out2[t] = 0.f;
  if (bid < 512) {                                // ---- x: block = (b, ck) ----
    const int b = bid >> 3, ck = bid & 7;
    #pragma unroll
    for (int j = 0; j < 4; j++) {                 // coalesced fp32 tile (64c x 64p)
      int e4 = j * 1024 + t * 4;
      int c = e4 >> 6, p0 = e4 & 63;
      float4 v = *(const float4*)(x + ((size_t)b * 512 + ck * 64 + c) * 64 + p0);
      tile[c][p0] = v.x; tile[c][p0 + 1] = v.y; tile[c][p0 + 2] = v.z; tile[c][p0 + 3] = v.w;
    }
    __syncthreads();
    #pragma unroll
    for (int i = 0; i < 2; i++) {                 // 512 16B-slots
      int s = i * 256 + t;
      int ksl = s >> 7, ph = (s >> 6) & 1, lane = s & 63;
      int cb = ksl * 16 + (lane >> 5) * 8, pp = ph * 32 + (lane & 31);
      u16 o[8];
      #pragma unroll
      for (int jj = 0; jj < 8; jj++) o[jj] = f2bf(tile[cb + jj][pp]);
      *(uint4*)(xF + (((size_t)b * 64 + (ck * 4 + ksl) * 2 + ph) * 512) + lane * 8) = *(uint4*)o;
    }
  } else if (bid < 1312) {                        // ---- W1: block = (k, ct), 800 ----
    const int wb = bid - 512, k = wb >> 3, ct = wb & 7;
    #pragma unroll
    for (int j = 0; j < 4; j++) {                 // 64 m-rows x 64 c-cols, coalesced
      int e4 = j * 1024 + t * 4;
      int r = e4 >> 6, c = e4 & 63;
      float4 v = *(const float4*)(w1 + ((size_t)k * 64 + r) * 512 + ct * 64 + c);
      tile[r][c] = v.x; tile[r][c + 1] = v.y; tile[r][c + 2] = v.z; tile[r][c + 3] = v.w;
    }
    __syncthreads();
    #pragma unroll
    for (int i = 0; i < 2; i++) {                 // 8 local frags (fr = ct*8 + frl)
      int s = i * 256 + t;
      int frl = s >> 6, lane = s & 63;
      int m = (frl & 1) * 32 + (lane & 31);
      int cl = (frl >> 1) * 16 + (lane >> 5) * 8;
      u16 o[8];
      #pragma unroll
      for (int jj = 0; jj < 8; jj++) o[jj] = f2bf(tile[m][cl + jj]);
      *(uint4*)(W1F + ((size_t)(k * 64 + ct * 8 + frl) * 512) + lane * 8) = *(uint4*)o;
    }
  } else if (bid < 1512) {                        // ---- W2: block = (k, mt), 200 ----
    const int wb = bid - 1312, k = wb >> 1, mt = wb & 1;
    #pragma unroll
    for (int j = 0; j < 4; j++) {                 // rows mt*64..+63, 64 cols
      int e4 = j * 1024 + t * 4;
      int r = e4 >> 6, c = e4 & 63;
      float4 v = *(const float4*)(w2 + ((size_t)k * 128 + mt * 64 + r) * 64 + c);
      tile[r][c] = v.x; tile[r][c + 1] = v.y; tile[r][c + 2] = v.z; tile[r][c + 3] = v.w;
    }
    __syncthreads();
    #pragma unroll
    for (int i = 0; i < 2; i++) {                 // frl = kb*2+m4l -> fr = kb*4+mt*2+m4l
      int s = i * 256 + t;
      int frl = s >> 6, lane = s & 63;
      int kb = frl >> 1, m4l = frl & 1;
      int ml = m4l * 32 + (lane & 31);
      int cl = kb * 16 + (lane >> 5) * 8;
      u16 o[8];
      #pragma unroll
      for (int jj = 0; jj < 8; jj++) o[jj] = f2bf(tile[ml][cl + jj]);
      *(uint4*)(W2F + ((size_t)(k * 16 + kb * 4 + mt * 2 + m4l) * 512) + lane * 8) = *(uint4*)o;
    }
  } else if (bid < 1612) {                        // ---- W3: block = k, 100 ----
    const int k = bid - 1512;
    #pragma unroll
    for (int j = 0; j < 4; j++) {                 // 32 rows x 128 cols, folded 2x64
      int e4 = j * 1024 + t * 4;
      int r = e4 >> 7, c = e4 & 127;
      float4 v = *(const float4*)(w3 + ((size_t)k * 32 + r) * 128 + c);
      int rr = r + ((c >> 6) << 5), cc = c & 63;
      tile[rr][cc] = v.x; tile[rr][cc + 1] = v.y; tile[rr][cc + 2] = v.z; tile[rr][cc + 3] = v.w;
    }
    __syncthreads();
    #pragma unroll
    for (int i = 0; i < 2; i++) {                 // fr = frl = kb
      int s = i * 256 + t;
      int frl = s >> 6, lane = s & 63;
      int m = lane & 31;
      int c0 = frl * 16 + (lane >> 5) * 8;        // 8-block never crosses the 64-split
      int rr = m + ((c0 >> 6) << 5), cc = c0 & 63;
      u16 o[8];
      #pragma unroll
      for (int jj = 0; jj < 8; jj++) o[jj] = f2bf(tile[rr][cc + jj]);
      *(uint4*)(W3F + ((size_t)(k * 8 + frl) * 512) + lane * 8) = *(uint4*)o;
    }
  } else {                                        // ---- zero fw/f1w/cnt (12900 floats) ----
    int i4 = (bid - 1612) * 256 + t;
    if (i4 < 3225) {
      float4 z = {0.f, 0.f, 0.f, 0.f};
      *(float4*)(fz + (size_t)i4 * 4) = z;
    }
  }
}

// ============ in-register C/D -> B-fragment handoff (T12-style) ============
// acc reg g*4+q holds act-row r = q+8g+4h (h=lane>>5), col = lane&31.
// Output B-frag covers act-rows [GG*16, GG*16+16): elem (half h, col nn)[j] =
// bf16(tanh(act[GG*16 + h*8 + j][nn])). One permlane32_swap per packed pair.
template<int GG>
__device__ __forceinline__ s16x8 mk_bfrag(const f32x16 a) {
  u32 P0 = pk2bf(tanh_fast(a[8 * GG + 0]), tanh_fast(a[8 * GG + 1]));
  u32 P1 = pk2bf(tanh_fast(a[8 * GG + 2]), tanh_fast(a[8 * GG + 3]));
  u32 Q0 = pk2bf(tanh_fast(a[8 * GG + 4]), tanh_fast(a[8 * GG + 5]));
  u32 Q1 = pk2bf(tanh_fast(a[8 * GG + 6]), tanh_fast(a[8 * GG + 7]));
  asm("v_permlane32_swap_b32 %0, %1" : "+v"(P0), "+v"(Q0));
  asm("v_permlane32_swap_b32 %0, %1" : "+v"(P1), "+v"(Q1));
  int4 wv = { (int)P0, (int)P1, (int)Q0, (int)Q1 };   // (j0,j1)(j2,j3)(j4,j5)(j6,j7)
  return __builtin_bit_cast(s16x8, wv);
}

// ============ main: block = (k, b-pair); waves = (bq, ph) -- r3 body ============
// + fused finalize: last-of-32 blocks per class k (device-scope cnt atomic, per
// guide m20 atomics are device-coherent) re-reads row k with agent-scope loads
// and reduces into out2. No grid sync, no cross-phase fence -> r6's L3-defeating
// coherence storm (FETCH 44->166 MB) cannot recur. Flag broadcast reuses dead
// pool[0..4) so LDS stays exactly 40960 (4 blocks/CU x 40960 = 160 KiB exactly).
__global__ __launch_bounds__(256, 4) void cssr_main(
    const u16* __restrict__ W1F, const u16* __restrict__ W2F, const u16* __restrict__ W3F,
    const u16* __restrict__ xF, const float* __restrict__ protos,
    const float* __restrict__ protos1, const int* __restrict__ ycls,
    float* __restrict__ out, float* __restrict__ fw, float* __restrict__ f1w,
    int* __restrict__ cnt, float* __restrict__ out2)
{
  // [0:4096) W1 buf0 | [4096:8192) W1 buf1 | [8192:16384) W2 | [16384:20480) W3
  __shared__ u16 pool[20480];          // 40 KB exactly
  const int bid = blockIdx.x;
  const int k = bid >> 5, bpair = bid & 31;
  const int tid = threadIdx.x, w = tid >> 6, lane = tid & 63;
  const int bq = w >> 1, ph = w & 1;
  const int b = bpair * 2 + bq;
  const int h = lane >> 5, nn = lane & 31;

  const u16* xw  = xF  + ((size_t)b * 64) * 512 + lane * 8;   // + (gks*2+ph)*512
  const u16* w1w = W1F + ((size_t)k * 64) * 512 + lane * 8;   // + (gks*2+mt)*512

  // prologue: chunk 0 -- x B-frags to regs, W1 frags (wave w -> ksl=w) to LDS
  s16x8 Bc[4], Bn[4];
  #pragma unroll
  for (int ksl = 0; ksl < 4; ksl++)
    Bc[ksl] = *(const s16x8*)(xw + (ksl * 2 + ph) * 512);
  ld_lds16(w1w + (w * 2 + 0) * 512, &pool[(2 * w + 0) * 512]);
  ld_lds16(w1w + (w * 2 + 1) * 512, &pool[(2 * w + 1) * 512]);

  // ---------------- stage 1: h1 = tanh(W1[k] @ x[b])  per-wave M=64 N=32 K=512 ----
  f32x16 acc1[2] = {};
  #pragma unroll
  for (int ci = 0; ci < 8; ci++) {
    const int cb = ci & 1;
    if (ci < 7) {                      // prefetch chunk ci+1: 4 reg-loads + 2 DMA
      #pragma unroll
      for (int ksl = 0; ksl < 4; ksl++)
        Bn[ksl] = *(const s16x8*)(xw + (((ci + 1) * 4 + ksl) * 2 + ph) * 512);
      ld_lds16(w1w + (((ci + 1) * 4 + w) * 2 + 0) * 512, &pool[(cb ^ 1) * 4096 + (2 * w + 0) * 512]);
      ld_lds16(w1w + (((ci + 1) * 4 + w) * 2 + 1) * 512, &pool[(cb ^ 1) * 4096 + (2 * w + 1) * 512]);
    } else {                           // last chunk: stage W2 (4/wave) + W3 (2/wave)
      #pragma unroll
      for (int j = 0; j < 4; j++)
        ld_lds16(W2F + ((size_t)k * 16 + w * 4 + j) * 512 + lane * 8,
                 &pool[8192 + (w * 4 + j) * 512]);
      ld_lds16(W3F + ((size_t)k * 8 + w * 2 + 0) * 512 + lane * 8, &pool[16384 + (w * 2 + 0) * 512]);
      ld_lds16(W3F + ((size_t)k * 8 + w * 2 + 1) * 512 + lane * 8, &pool[16384 + (w * 2 + 1) * 512]);
    }
    VMCNT(6); BAR();                   // chunk ci resident; 6 newest stay in flight
    __builtin_amdgcn_s_setprio(1);
    #pragma unroll
    for (int ksl = 0; ksl < 4; ksl++) {
      s16x8 A0 = *(const s16x8*)&pool[cb * 4096 + (ksl * 2 + 0) * 512 + lane * 8];
      s16x8 A1 = *(const s16x8*)&pool[cb * 4096 + (ksl * 2 + 1) * 512 + lane * 8];
      acc1[0] = MFMA32(A0, Bc[ksl], acc1[0]);
      acc1[1] = MFMA32(A1, Bc[ksl], acc1[1]);
    }
    __builtin_amdgcn_s_setprio(0);
    if (ci < 7) {
      #pragma unroll
      for (int ksl = 0; ksl < 4; ksl++) Bc[ksl] = Bn[ksl];
      BAR();                           // reads of buf cb done -> reusable for DMA
    }
  }

  // handoff 1 (in-register, overlaps W2/W3 DMA): b1[kb] = h1 ch [kb*16,kb*16+16)
  s16x8 b1[4];
  b1[0] = mk_bfrag<0>(acc1[0]); b1[1] = mk_bfrag<1>(acc1[0]);
  b1[2] = mk_bfrag<0>(acc1[1]); b1[3] = mk_bfrag<1>(acc1[1]);

  VMCNT(2); BAR();                     // W2 resident (W3's 2 still in flight)

  // ---------------- stage 2: h2 = tanh(W2[k] @ h1)  per-wave M=128 N=32 K=64 ----
  f32x16 acc2[4] = {};
  __builtin_amdgcn_s_setprio(1);
  #pragma unroll
  for (int kb = 0; kb < 4; kb++) {
    #pragma unroll
    for (int m4 = 0; m4 < 4; m4++) {
      s16x8 A = *(const s16x8*)&pool[8192 + (kb * 4 + m4) * 512 + lane * 8];
      acc2[m4] = MFMA32(A, b1[kb], acc2[m4]);
    }
  }
  __builtin_amdgcn_s_setprio(0);

  VMCNT(0); BAR();                     // W3 resident

  // prefetch protos into regs (latency hides under handoff-2's 64 tanh)
  const int p = ph * 32 + nn;
  const float* pr  = protos  + (size_t)k * 2048 + p;
  const float* pr1 = protos1 + (size_t)k * 2048 + p;
  float prv[16], pr1v[16];
  #pragma unroll
  for (int g = 0; g < 4; g++) {
    #pragma unroll
    for (int q = 0; q < 4; q++) {
      int m = q + 8 * g + 4 * h;
      prv [g * 4 + q] = pr [m * 64];
      pr1v[g * 4 + q] = pr1[m * 64];
    }
  }

  // handoff 2
  s16x8 b2[8];
  b2[0] = mk_bfrag<0>(acc2[0]); b2[1] = mk_bfrag<1>(acc2[0]);
  b2[2] = mk_bfrag<0>(acc2[1]); b2[3] = mk_bfrag<1>(acc2[1]);
  b2[4] = mk_bfrag<0>(acc2[2]); b2[5] = mk_bfrag<1>(acc2[2]);
  b2[6] = mk_bfrag<0>(acc2[3]); b2[7] = mk_bfrag<1>(acc2[3]);

  // ---------------- stage 3: lt = tanh(W3[k] @ h2)  per-wave M=32 N=32 K=128 ----
  f32x16 acc3 = {};
  __builtin_amdgcn_s_setprio(1);
  #pragma unroll
  for (int kb = 0; kb < 8; kb++) {
    s16x8 A = *(const s16x8*)&pool[16384 + kb * 512 + lane * 8];
    acc3 = MFMA32(A, b2[kb], acc3);
  }
  __builtin_amdgcn_s_setprio(0);

  // ---------------- distances, clip, logits, f / f1 ----------------
  float d2 = 0.f, d21 = 0.f;
  #pragma unroll
  for (int g = 0; g < 4; g++) {
    #pragma unroll
    for (int q = 0; q < 4; q++) {
      float lt = tanh_fast(acc3[g * 4 + q]);
      float d = lt - prv [g * 4 + q];  d2  += d * d;
      float e = lt - pr1v[g * 4 + q];  d21 += e * e;
    }
  }
  d2 += __shfl_xor(d2, 32); d21 += __shfl_xor(d21, 32);
  float er  = fminf(fmaxf(d2  * -0.1f, -100.f), 100.f);
  float er1 = fminf(fmaxf(d21 * -0.1f, -100.f), 100.f);
  if (h == 0) {
    out[(size_t)b * 6400 + k * 64 + p]          = er;
    out[409600 + (size_t)b * 6400 + k * 64 + p] = er1;
  }
  float s = er, s1 = er1;
  s += __shfl_xor(s, 1);  s1 += __shfl_xor(s1, 1);
  s += __shfl_xor(s, 2);  s1 += __shfl_xor(s1, 2);
  s += __shfl_xor(s, 4);  s1 += __shfl_xor(s1, 4);
  s += __shfl_xor(s, 8);  s1 += __shfl_xor(s1, 8);
  s += __shfl_xor(s, 16); s1 += __shfl_xor(s1, 16);
  if (lane == 0) {
    atomicAdd(&fw [k * 64 + b], s);    // two waves (ph=0,1) contribute per (k,b)
    atomicAdd(&f1w[k * 64 + b], s1);
  }

  // ---------------- fused finalize: last block of class k reduces row k ----------
  volatile int* lflag = (volatile int*)pool;   // pool reads all done above
  __threadfence();                     // make our fw/f1w adds device-visible
  __syncthreads();                     // all 4 waves' adds issued before counting
  if (tid == 0) *lflag = (atomicAdd(&cnt[k], 1) == 31) ? 1 : 0;
  __syncthreads();
  if (*lflag && tid < 64) {
    const int bb = tid;
    float fv  = __hip_atomic_load(fw  + k * 64 + bb, __ATOMIC_RELAXED, __HIP_MEMORY_SCOPE_AGENT);
    float f1v = __hip_atomic_load(f1w + k * 64 + bb, __ATOMIC_RELAXED, __HIP_MEMORY_SCOPE_AGENT);
    bool eq  = (ycls[bb] == k);
    bool cb2 = (!eq) && (fv < 10000.f);
    float s1r = eq ? f1v : 0.f, ne = eq ? 1.f : 0.f;
    float sr  = cb2 ? fv  : 0.f, nc = cb2 ? 1.f : 0.f;
    #pragma unroll
    for (int o = 1; o < 64; o <<= 1) {
      s1r += __shfl_xor(s1r, o); ne += __shfl_xor(ne, o);
      sr  += __shfl_xor(sr,  o); nc += __shfl_xor(nc, o);
    }
    if (bb == 0) {
      if (ne > 0.f) atomicAdd(&out2[0], s1r / ne);
      if (nc > 0.f) atomicAdd(&out2[1], sr / nc);
    }
  }
}

extern "C" void kernel_launch(void* const* d_in, const int* in_sizes, int n_in,
                              void* d_out, int out_size, void* d_ws, size_t ws_size,
                              hipStream_t stream) {
  const float* x     = (const float*)d_in[0];
  const int*   ycls  = (const int*)d_in[1];
  const float* W1    = (const float*)d_in[4];
  const float* W2    = (const float*)d_in[5];
  const float* W3    = (const float*)d_in[6];
  const float* prot  = (const float*)d_in[7];
  const float* prot1 = (const float*)d_in[8];
  float* out = (float*)d_out;

  char* ws = (char*)d_ws;
  u16*  xFb = (u16*)(ws);                        // 4,194,304 B
  u16*  W1F = (u16*)(ws + 4194304);              // 6,553,600 B
  u16*  W2F = (u16*)(ws + 10747904);             // 1,638,400 B
  u16*  W3F = (u16*)(ws + 12386304);             //   819,200 B
  float* fw  = (float*)(ws + 13205504);          // 25,600 B
  float* f1w = (float*)(ws + 13231104);          // 25,600 B
  int*   cnt = (int*)  (ws + 13256704);          //     400 B (zeroed with fw/f1w)
  float* out2 = out + 819200;

  prep<<<1625, 256, 0, stream>>>(x, W1, W2, W3, xFb, W1F, W2F, W3F, fw, out2);
  cssr_main<<<KCLS * 32, 256, 0, stream>>>(W1F, W2F, W3F, xFb, prot, prot1, ycls,
                                           out, fw, f1w, cnt, out2);
}

// Round 8
// 141.149 us; speedup vs baseline: 2.8501x; 2.8501x over previous
//
#include <hip/hip_runtime.h>

typedef short  s16x8  __attribute__((ext_vector_type(8)));
typedef float  f32x16 __attribute__((ext_vector_type(16)));
typedef unsigned short u16;
typedef unsigned int   u32;

#define MFMA32(a,b,c) __builtin_amdgcn_mfma_f32_32x32x16_bf16((a),(b),(c),0,0,0)
#define KCLS 100
#define VMCNT(n) asm volatile("s_waitcnt vmcnt(" #n ")" ::: "memory")
#define BAR()    __builtin_amdgcn_s_barrier()

__device__ __forceinline__ u16 f2bf(float f) {
  return (u16)(__builtin_bit_cast(unsigned, f) >> 16);   // trunc; error budget huge
}

__device__ __forceinline__ u32 pk2bf(float lo, float hi) {   // trunc-pack 2 f32 -> 2 bf16
#if __has_builtin(__builtin_amdgcn_perm)
  return __builtin_amdgcn_perm(__builtin_bit_cast(u32, hi),
                               __builtin_bit_cast(u32, lo), 0x07060302u);
#else
  return (__builtin_bit_cast(u32, lo) >> 16) | (__builtin_bit_cast(u32, hi) & 0xffff0000u);
#endif
}

__device__ __forceinline__ float tanh_fast(float x) {
  float e = __builtin_amdgcn_exp2f(x * 2.8853900817779268f);
  return 1.0f - 2.0f * __builtin_amdgcn_rcpf(e + 1.0f);
}

__device__ __forceinline__ void ld_lds16(const void* g, void* l) {
  __builtin_amdgcn_global_load_lds(
      (const __attribute__((address_space(1))) unsigned char*)g,
      (__attribute__((address_space(3))) unsigned char*)l, 16, 0, 0);
}

// ============ prep: emit fragment-ordered bf16 tensors + zero accumulators ============
// r5-proven: every branch is coalesced fp32 tile load -> LDS transpose (stride-65,
// conflict-free) -> uint4 frag writes.
// Fragment = 1 KB: [lane64][8 bf16]; lane&31 = row/col-in-tile, lane>>5 = k-half.
// xF  [b][frag = gks*2+ph]   p = ph*32+(lane&31), c = gks*16+(lane>>5)*8+j
// W1F [k][frag = gks*2+mt]   m = mt*32+(lane&31), c = (frag>>1)*16+(lane>>5)*8+j
// W2F [k][frag = kb*4+m4]    m = m4*32+(lane&31), c = kb*16+(lane>>5)*8+j
// W3F [k][frag = kb]         m = lane&31,         c = kb*16+(lane>>5)*8+j
__global__ void prep(const float* __restrict__ x, const float* __restrict__ w1,
                     const float* __restrict__ w2, const float* __restrict__ w3,
                     u16* __restrict__ xF, u16* __restrict__ W1F,
                     u16* __restrict__ W2F, u16* __restrict__ W3F,
                     float* __restrict__ fz, float* __restrict__ out2) {
  __shared__ float tile[64][65];
  const int bid = blockIdx.x, t = threadIdx.x;
  if (bid == 0 && t < 2) out2[t] = 0.f;
  if (bid < 512) {                                // ---- x: block = (b, ck) ----
    const int b = bid >> 3, ck = bid & 7;
    #pragma unroll
    for (int j = 0; j < 4; j++) {                 // coalesced fp32 tile (64c x 64p)
      int e4 = j * 1024 + t * 4;
      int c = e4 >> 6, p0 = e4 & 63;
      float4 v = *(const float4*)(x + ((size_t)b * 512 + ck * 64 + c) * 64 + p0);
      tile[c][p0] = v.x; tile[c][p0 + 1] = v.y; tile[c][p0 + 2] = v.z; tile[c][p0 + 3] = v.w;
    }
    __syncthreads();
    #pragma unroll
    for (int i = 0; i < 2; i++) {                 // 512 16B-slots
      int s = i * 256 + t;
      int ksl = s >> 7, ph = (s >> 6) & 1, lane = s & 63;
      int cb = ksl * 16 + (lane >> 5) * 8, pp = ph * 32 + (lane & 31);
      u16 o[8];
      #pragma unroll
      for (int jj = 0; jj < 8; jj++) o[jj] = f2bf(tile[cb + jj][pp]);
      *(uint4*)(xF + (((size_t)b * 64 + (ck * 4 + ksl) * 2 + ph) * 512) + lane * 8) = *(uint4*)o;
    }
  } else if (bid < 1312) {                        // ---- W1: block = (k, ct), 800 ----
    const int wb = bid - 512, k = wb >> 3, ct = wb & 7;
    #pragma unroll
    for (int j = 0; j < 4; j++) {                 // 64 m-rows x 64 c-cols, coalesced
      int e4 = j * 1024 + t * 4;
      int r = e4 >> 6, c = e4 & 63;
      float4 v = *(const float4*)(w1 + ((size_t)k * 64 + r) * 512 + ct * 64 + c);
      tile[r][c] = v.x; tile[r][c + 1] = v.y; tile[r][c + 2] = v.z; tile[r][c + 3] = v.w;
    }
    __syncthreads();
    #pragma unroll
    for (int i = 0; i < 2; i++) {                 // 8 local frags (fr = ct*8 + frl)
      int s = i * 256 + t;
      int frl = s >> 6, lane = s & 63;
      int m = (frl & 1) * 32 + (lane & 31);
      int cl = (frl >> 1) * 16 + (lane >> 5) * 8;
      u16 o[8];
      #pragma unroll
      for (int jj = 0; jj < 8; jj++) o[jj] = f2bf(tile[m][cl + jj]);
      *(uint4*)(W1F + ((size_t)(k * 64 + ct * 8 + frl) * 512) + lane * 8) = *(uint4*)o;
    }
  } else if (bid < 1512) {                        // ---- W2: block = (k, mt), 200 ----
    const int wb = bid - 1312, k = wb >> 1, mt = wb & 1;
    #pragma unroll
    for (int j = 0; j < 4; j++) {                 // rows mt*64..+63, 64 cols
      int e4 = j * 1024 + t * 4;
      int r = e4 >> 6, c = e4 & 63;
      float4 v = *(const float4*)(w2 + ((size_t)k * 128 + mt * 64 + r) * 64 + c);
      tile[r][c] = v.x; tile[r][c + 1] = v.y; tile[r][c + 2] = v.z; tile[r][c + 3] = v.w;
    }
    __syncthreads();
    #pragma unroll
    for (int i = 0; i < 2; i++) {                 // frl = kb*2+m4l -> fr = kb*4+mt*2+m4l
      int s = i * 256 + t;
      int frl = s >> 6, lane = s & 63;
      int kb = frl >> 1, m4l = frl & 1;
      int ml = m4l * 32 + (lane & 31);
      int cl = kb * 16 + (lane >> 5) * 8;
      u16 o[8];
      #pragma unroll
      for (int jj = 0; jj < 8; jj++) o[jj] = f2bf(tile[ml][cl + jj]);
      *(uint4*)(W2F + ((size_t)(k * 16 + kb * 4 + mt * 2 + m4l) * 512) + lane * 8) = *(uint4*)o;
    }
  } else if (bid < 1612) {                        // ---- W3: block = k, 100 ----
    const int k = bid - 1512;
    #pragma unroll
    for (int j = 0; j < 4; j++) {                 // 32 rows x 128 cols, folded 2x64
      int e4 = j * 1024 + t * 4;
      int r = e4 >> 7, c = e4 & 127;
      float4 v = *(const float4*)(w3 + ((size_t)k * 32 + r) * 128 + c);
      int rr = r + ((c >> 6) << 5), cc = c & 63;
      tile[rr][cc] = v.x; tile[rr][cc + 1] = v.y; tile[rr][cc + 2] = v.z; tile[rr][cc + 3] = v.w;
    }
    __syncthreads();
    #pragma unroll
    for (int i = 0; i < 2; i++) {                 // fr = frl = kb
      int s = i * 256 + t;
      int frl = s >> 6, lane = s & 63;
      int m = lane & 31;
      int c0 = frl * 16 + (lane >> 5) * 8;        // 8-block never crosses the 64-split
      int rr = m + ((c0 >> 6) << 5), cc = c0 & 63;
      u16 o[8];
      #pragma unroll
      for (int jj = 0; jj < 8; jj++) o[jj] = f2bf(tile[rr][cc + jj]);
      *(uint4*)(W3F + ((size_t)(k * 8 + frl) * 512) + lane * 8) = *(uint4*)o;
    }
  } else {                                        // ---- zero fw/f1w (12800 floats) ----
    int i4 = (bid - 1612) * 256 + t;
    if (i4 < 3200) {
      float4 z = {0.f, 0.f, 0.f, 0.f};
      *(float4*)(fz + (size_t)i4 * 4) = z;
    }
  }
}

// ============ in-register C/D -> B-fragment handoff (T12-style) ============
// acc reg g*4+q holds act-row r = q+8g+4h (h=lane>>5), col = lane&31.
// Output B-frag covers act-rows [GG*16, GG*16+16): elem (half h, col nn)[j] =
// bf16(tanh(act[GG*16 + h*8 + j][nn])). One permlane32_swap per packed pair.
template<int GG>
__device__ __forceinline__ s16x8 mk_bfrag(const f32x16 a) {
  u32 P0 = pk2bf(tanh_fast(a[8 * GG + 0]), tanh_fast(a[8 * GG + 1]));
  u32 P1 = pk2bf(tanh_fast(a[8 * GG + 2]), tanh_fast(a[8 * GG + 3]));
  u32 Q0 = pk2bf(tanh_fast(a[8 * GG + 4]), tanh_fast(a[8 * GG + 5]));
  u32 Q1 = pk2bf(tanh_fast(a[8 * GG + 6]), tanh_fast(a[8 * GG + 7]));
  asm("v_permlane32_swap_b32 %0, %1" : "+v"(P0), "+v"(Q0));
  asm("v_permlane32_swap_b32 %0, %1" : "+v"(P1), "+v"(Q1));
  int4 wv = { (int)P0, (int)P1, (int)Q0, (int)Q1 };   // (j0,j1)(j2,j3)(j4,j5)(j6,j7)
  return __builtin_bit_cast(s16x8, wv);
}

// ============ main: block = (k, b-pair); waves = (bq, ph) -- r3 body restored ======
// r8 edits vs proven r5/r3 (58.2 us): (1) W2/W3 DMA issued at ci=6 (their LDS
// regions are untouched all of stage 1, so issue one chunk early -> extra latency
// cover, uniform last iteration; vmcnt bookkeeping: ci=6 issues 12 -> VMCNT(12);
// ci=7 issues 0 -> VMCNT(6) drains B(7)/W1(7), leaves W2/W3 as the 6 newest).
// (2) no setprio in lockstep stage 1 (T5/m190: null-to-negative when waves are
// barrier-locked in phase); kept for phase-diverse stages 2/3.
__global__ __launch_bounds__(256, 4) void cssr_main(
    const u16* __restrict__ W1F, const u16* __restrict__ W2F, const u16* __restrict__ W3F,
    const u16* __restrict__ xF, const float* __restrict__ protos,
    const float* __restrict__ protos1, float* __restrict__ out,
    float* __restrict__ fw, float* __restrict__ f1w)
{
  // [0:4096) W1 buf0 | [4096:8192) W1 buf1 | [8192:16384) W2 | [16384:20480) W3
  __shared__ u16 pool[20480];          // 40 KB
  const int bid = blockIdx.x;
  const int k = bid >> 5, bpair = bid & 31;
  const int tid = threadIdx.x, w = tid >> 6, lane = tid & 63;
  const int bq = w >> 1, ph = w & 1;
  const int b = bpair * 2 + bq;
  const int h = lane >> 5, nn = lane & 31;

  const u16* xw  = xF  + ((size_t)b * 64) * 512 + lane * 8;   // + (gks*2+ph)*512
  const u16* w1w = W1F + ((size_t)k * 64) * 512 + lane * 8;   // + (gks*2+mt)*512

  // prologue: chunk 0 -- x B-frags to regs, W1 frags (wave w -> ksl=w) to LDS
  s16x8 Bc[4], Bn[4];
  #pragma unroll
  for (int ksl = 0; ksl < 4; ksl++)
    Bc[ksl] = *(const s16x8*)(xw + (ksl * 2 + ph) * 512);
  ld_lds16(w1w + (w * 2 + 0) * 512, &pool[(2 * w + 0) * 512]);
  ld_lds16(w1w + (w * 2 + 1) * 512, &pool[(2 * w + 1) * 512]);

  // ---------------- stage 1: h1 = tanh(W1[k] @ x[b])  per-wave M=64 N=32 K=512 ----
  f32x16 acc1[2] = {};
  #pragma unroll
  for (int ci = 0; ci < 8; ci++) {
    const int cb = ci & 1;
    if (ci < 7) {                      // prefetch chunk ci+1: 4 reg-loads + 2 DMA
      #pragma unroll
      for (int ksl = 0; ksl < 4; ksl++)
        Bn[ksl] = *(const s16x8*)(xw + (((ci + 1) * 4 + ksl) * 2 + ph) * 512);
      ld_lds16(w1w + (((ci + 1) * 4 + w) * 2 + 0) * 512, &pool[(cb ^ 1) * 4096 + (2 * w + 0) * 512]);
      ld_lds16(w1w + (((ci + 1) * 4 + w) * 2 + 1) * 512, &pool[(cb ^ 1) * 4096 + (2 * w + 1) * 512]);
      if (ci == 6) {                   // early W2 (4/wave) + W3 (2/wave): regions idle
        #pragma unroll
        for (int j = 0; j < 4; j++)
          ld_lds16(W2F + ((size_t)k * 16 + w * 4 + j) * 512 + lane * 8,
                   &pool[8192 + (w * 4 + j) * 512]);
        ld_lds16(W3F + ((size_t)k * 8 + w * 2 + 0) * 512 + lane * 8, &pool[16384 + (w * 2 + 0) * 512]);
        ld_lds16(W3F + ((size_t)k * 8 + w * 2 + 1) * 512 + lane * 8, &pool[16384 + (w * 2 + 1) * 512]);
      }
    }
    if (ci == 6) { VMCNT(12); } else { VMCNT(6); }   // counted: chunk ci resident
    BAR();
    #pragma unroll
    for (int ksl = 0; ksl < 4; ksl++) {
      s16x8 A0 = *(const s16x8*)&pool[cb * 4096 + (ksl * 2 + 0) * 512 + lane * 8];
      s16x8 A1 = *(const s16x8*)&pool[cb * 4096 + (ksl * 2 + 1) * 512 + lane * 8];
      acc1[0] = MFMA32(A0, Bc[ksl], acc1[0]);
      acc1[1] = MFMA32(A1, Bc[ksl], acc1[1]);
    }
    if (ci < 7) {
      #pragma unroll
      for (int ksl = 0; ksl < 4; ksl++) Bc[ksl] = Bn[ksl];
      BAR();                           // reads of buf cb done -> reusable for DMA
    }
  }

  // handoff 1 (in-register, overlaps W2/W3 DMA): b1[kb] = h1 ch [kb*16,kb*16+16)
  s16x8 b1[4];
  b1[0] = mk_bfrag<0>(acc1[0]); b1[1] = mk_bfrag<1>(acc1[0]);
  b1[2] = mk_bfrag<0>(acc1[1]); b1[3] = mk_bfrag<1>(acc1[1]);

  VMCNT(2); BAR();                     // W2 resident (W3's 2 may still be in flight)

  // ---------------- stage 2: h2 = tanh(W2[k] @ h1)  per-wave M=128 N=32 K=64 ----
  f32x16 acc2[4] = {};
  __builtin_amdgcn_s_setprio(1);
  #pragma unroll
  for (int kb = 0; kb < 4; kb++) {
    #pragma unroll
    for (int m4 = 0; m4 < 4; m4++) {
      s16x8 A = *(const s16x8*)&pool[8192 + (kb * 4 + m4) * 512 + lane * 8];
      acc2[m4] = MFMA32(A, b1[kb], acc2[m4]);
    }
  }
  __builtin_amdgcn_s_setprio(0);

  VMCNT(0); BAR();                     // W3 resident; no barriers after this point

  // prefetch protos into regs (latency hides under handoff-2's 64 tanh)
  const int p = ph * 32 + nn;
  const float* pr  = protos  + (size_t)k * 2048 + p;
  const float* pr1 = protos1 + (size_t)k * 2048 + p;
  float prv[16], pr1v[16];
  #pragma unroll
  for (int g = 0; g < 4; g++) {
    #pragma unroll
    for (int q = 0; q < 4; q++) {
      int m = q + 8 * g + 4 * h;
      prv [g * 4 + q] = pr [m * 64];
      pr1v[g * 4 + q] = pr1[m * 64];
    }
  }

  // handoff 2
  s16x8 b2[8];
  b2[0] = mk_bfrag<0>(acc2[0]); b2[1] = mk_bfrag<1>(acc2[0]);
  b2[2] = mk_bfrag<0>(acc2[1]); b2[3] = mk_bfrag<1>(acc2[1]);
  b2[4] = mk_bfrag<0>(acc2[2]); b2[5] = mk_bfrag<1>(acc2[2]);
  b2[6] = mk_bfrag<0>(acc2[3]); b2[7] = mk_bfrag<1>(acc2[3]);

  // ---------------- stage 3: lt = tanh(W3[k] @ h2)  per-wave M=32 N=32 K=128 ----
  f32x16 acc3 = {};
  __builtin_amdgcn_s_setprio(1);
  #pragma unroll
  for (int kb = 0; kb < 8; kb++) {
    s16x8 A = *(const s16x8*)&pool[16384 + kb * 512 + lane * 8];
    acc3 = MFMA32(A, b2[kb], acc3);
  }
  __builtin_amdgcn_s_setprio(0);

  // ---------------- distances, clip, logits, f / f1 ----------------
  float d2 = 0.f, d21 = 0.f;
  #pragma unroll
  for (int g = 0; g < 4; g++) {
    #pragma unroll
    for (int q = 0; q < 4; q++) {
      float lt = tanh_fast(acc3[g * 4 + q]);
      float d = lt - prv [g * 4 + q];  d2  += d * d;
      float e = lt - pr1v[g * 4 + q];  d21 += e * e;
    }
  }
  d2 += __shfl_xor(d2, 32); d21 += __shfl_xor(d21, 32);
  float er  = fminf(fmaxf(d2  * -0.1f, -100.f), 100.f);
  float er1 = fminf(fmaxf(d21 * -0.1f, -100.f), 100.f);
  if (h == 0) {
    out[(size_t)b * 6400 + k * 64 + p]          = er;
    out[409600 + (size_t)b * 6400 + k * 64 + p] = er1;
  }
  float s = er, s1 = er1;
  s += __shfl_xor(s, 1);  s1 += __shfl_xor(s1, 1);
  s += __shfl_xor(s, 2);  s1 += __shfl_xor(s1, 2);
  s += __shfl_xor(s, 4);  s1 += __shfl_xor(s1, 4);
  s += __shfl_xor(s, 8);  s1 += __shfl_xor(s1, 8);
  s += __shfl_xor(s, 16); s1 += __shfl_xor(s1, 16);
  if (lane == 0) {
    atomicAdd(&fw [k * 64 + b], s);    // two waves (ph=0,1) contribute per (k,b)
    atomicAdd(&f1w[k * 64 + b], s1);
  }
}

// ============ finalize: per-k block, atomicAdd into out2 (zeroed in prep) ============
// Kept as a separate dispatch ON PURPOSE: the dispatch boundary is the ordering
// primitive. In-kernel alternatives need device-scope fences which, on 8-XCD
// MI355X, wreck L2 locality for all in-flight blocks (r7: 62 -> 327 us).
__global__ void finalize(const float* __restrict__ f, const float* __restrict__ f1,
                         const int* __restrict__ ycls, float* __restrict__ out2) {
  const int k = blockIdx.x, b = threadIdx.x;
  float fv = f[k * 64 + b], f1v = f1[k * 64 + b];
  bool eq = (ycls[b] == k);
  bool cb = (!eq) && (fv < 10000.f);
  float s1 = eq ? f1v : 0.f, ne = eq ? 1.f : 0.f;
  float s  = cb ? fv  : 0.f, nc = cb ? 1.f : 0.f;
  #pragma unroll
  for (int o = 1; o < 64; o <<= 1) {
    s1 += __shfl_xor(s1, o); ne += __shfl_xor(ne, o);
    s  += __shfl_xor(s,  o); nc += __shfl_xor(nc, o);
  }
  if (b == 0) {
    if (ne > 0.f) atomicAdd(&out2[0], s1 / ne);
    if (nc > 0.f) atomicAdd(&out2[1], s / nc);
  }
}

extern "C" void kernel_launch(void* const* d_in, const int* in_sizes, int n_in,
                              void* d_out, int out_size, void* d_ws, size_t ws_size,
                              hipStream_t stream) {
  const float* x     = (const float*)d_in[0];
  const int*   ycls  = (const int*)d_in[1];
  const float* W1    = (const float*)d_in[4];
  const float* W2    = (const float*)d_in[5];
  const float* W3    = (const float*)d_in[6];
  const float* prot  = (const float*)d_in[7];
  const float* prot1 = (const float*)d_in[8];
  float* out = (float*)d_out;

  char* ws = (char*)d_ws;
  u16*  xFb = (u16*)(ws);                        // 4,194,304 B
  u16*  W1F = (u16*)(ws + 4194304);              // 6,553,600 B
  u16*  W2F = (u16*)(ws + 10747904);             // 1,638,400 B
  u16*  W3F = (u16*)(ws + 12386304);             //   819,200 B
  float* fw  = (float*)(ws + 13205504);          // 25,600 B
  float* f1w = (float*)(ws + 13231104);          // 25,600 B (contiguous with fw)
  float* out2 = out + 819200;

  prep<<<1625, 256, 0, stream>>>(x, W1, W2, W3, xFb, W1F, W2F, W3F, fw, out2);
  cssr_main<<<KCLS * 32, 256, 0, stream>>>(W1F, W2F, W3F, xFb, prot, prot1,
                                           out, fw, f1w);
  finalize<<<KCLS, 64, 0, stream>>>(fw, f1w, ycls, out2);
}